// Round 1
// baseline (531.152 us; speedup 1.0000x reference)
//
#include <hip/hip_runtime.h>

// MoE Router (Switch), fully fused.
// logits = x@W + b; top-3 one-hot mask; softmax probs; importance = load = col-sum.
// x: [N=32768, D=2048] f32, W: [D, E=64] f32, b: [E] f32.
// out = [mask (N*E) | prob (N*E) | importance (E) | load (E)]  (f32)
//
// R5 (fusion): one 512-thread block per 64 rows.
//   Waves 0-3: K-half 0, 16 experts each (e0 = 16*wg) — VERIFIED R4 inner loop.
//   Waves 4-7: K-half 1, same expert slices; partials parked in (dead) buffer B.
//   Epilogue per-lane (lane = row): combine halves + bias, 16-elem insertion
//   top-3 (strict > keeps lowest index on ties, matching jax top_k), cross-wave
//   merge of 4x3 candidates via LDS, softmax from registered exps, coalesced
//   float4 mask/prob stores, butterfly column-sums -> pws[E][512].
//   Kills the pl round-trip (67 MB) and the 4-tree/row shuffle epilogue kernel.

#define D_MODEL 2048
#define N_EXP   64
#define BK      64
#define XPITCH  68            // pad 64 -> 68 words: 16B-aligned float4 rows
#define KHALF   (D_MODEL / 2)
#define NBLK    512           // 32768 / 64 rows per block

__global__ __launch_bounds__(512, 4) void fused_kernel(
    const float* __restrict__ x, const float* __restrict__ W,
    const float* __restrict__ b,
    float* __restrict__ out_mask, float* __restrict__ out_prob,
    float* __restrict__ pws) {

    __shared__ float lds[2 * 64 * XPITCH];   // 34816 B (two staging buffers)

    const int tid   = threadIdx.x;
    const int lane  = tid & 63;
    const int wv    = __builtin_amdgcn_readfirstlane(tid >> 6);  // 0..7
    const int grp   = wv >> 2;               // 0: K-half 0, 1: K-half 1
    const int wg    = wv & 3;                // wave within group
    const int e0    = wg * 16;
    const int gtid  = tid & 255;
    const int rg    = blockIdx.x;            // rows rg*64 .. +63
    const int kbase = grp * KHALF;

    float* __restrict__ Xg = lds + grp * (64 * XPITCH);

    float acc[16];
#pragma unroll
    for (int e = 0; e < 16; ++e) acc[e] = 0.0f;

    // staging map (per 256-thread group): row = gtid>>4 (+j*16), 16 float4/row
    const int srow = gtid >> 4;
    const int skk4 = gtid & 15;

    for (int c = 0; c < KHALF; c += BK) {
        float4 tmp[4];
#pragma unroll
        for (int j = 0; j < 4; ++j)
            tmp[j] = *(const float4*)(x + (size_t)(rg * 64 + srow + j * 16) * D_MODEL
                                        + kbase + c + skk4 * 4);
        __syncthreads();                     // prev chunk fully consumed
#pragma unroll
        for (int j = 0; j < 4; ++j)
            *(float4*)&Xg[(srow + j * 16) * XPITCH + skk4 * 4] = tmp[j];
        __syncthreads();

#pragma unroll 4
        for (int kk4 = 0; kk4 < BK / 4; ++kk4) {
            const float4 xv = *(const float4*)&Xg[lane * XPITCH + kk4 * 4];
            const float* wp = W + (size_t)(kbase + c + kk4 * 4) * N_EXP + e0;
#pragma unroll
            for (int j = 0; j < 4; ++j) {
                const float xs = ((const float*)&xv)[j];
#pragma unroll
                for (int e = 0; e < 16; ++e)
                    acc[e] = fmaf(xs, wp[j * N_EXP + e], acc[e]);  // s_load W
            }
        }
    }

    __syncthreads();   // sync1: all staging reads complete, buffers reusable

    // upper group parks partials in (former) buffer B: [4][64][17] (padded)
    if (grp == 1) {
        float* dst = lds + 64 * XPITCH + (wg * 64 + lane) * 17;
#pragma unroll
        for (int e = 0; e < 16; ++e) dst[e] = acc[e];
    }
    __syncthreads();   // sync2

    float v[16], pe[16];
    float x1 = 0.0f; int i1 = -1, i2 = -1, i3 = -1;

    if (grp == 0) {
        const float* src = lds + 64 * XPITCH + (wg * 64 + lane) * 17;
#pragma unroll
        for (int e = 0; e < 16; ++e) v[e] = acc[e] + src[e] + b[e0 + e];

        // per-lane top-3 of 16 (ascending e scan + strict > == lowest-index ties)
        float t1 = -INFINITY, t2 = -INFINITY, t3 = -INFINITY;
        int   j1 = 0, j2 = 0, j3 = 0;
#pragma unroll
        for (int e = 0; e < 16; ++e) {
            const float xv = v[e]; const int g = e0 + e;
            if (xv > t1)      { t3 = t2; j3 = j2; t2 = t1; j2 = j1; t1 = xv; j1 = g; }
            else if (xv > t2) { t3 = t2; j3 = j2; t2 = xv; j2 = g; }
            else if (xv > t3) { t3 = xv; j3 = g; }
        }
        float* cand = lds + (wg * 64 + lane) * 8;   // buffer-A region, 8 KB
        cand[0] = t1; cand[1] = __int_as_float(j1);
        cand[2] = t2; cand[3] = __int_as_float(j2);
        cand[4] = t3; cand[5] = __int_as_float(j3);
    }
    __syncthreads();   // sync3

    if (grp == 0) {
        // merge 4 waves x 3 candidates; scan order is expert-ascending, so
        // linear scan with strict > keeps the lowest index on ties.
        float bv[12]; int bg[12];
#pragma unroll
        for (int w = 0; w < 4; ++w) {
            const float* cp = lds + (w * 64 + lane) * 8;
#pragma unroll
            for (int k = 0; k < 3; ++k) {
                bv[w * 3 + k] = cp[2 * k];
                bg[w * 3 + k] = __float_as_int(cp[2 * k + 1]);
            }
        }
#pragma unroll
        for (int pick = 0; pick < 3; ++pick) {
            float mv = bv[0]; int mg = bg[0]; int mk = 0;
#pragma unroll
            for (int k = 1; k < 12; ++k)
                if (bv[k] > mv) { mv = bv[k]; mg = bg[k]; mk = k; }
            if (pick == 0)      { x1 = mv; i1 = mg; }
            else if (pick == 1) { i2 = mg; }
            else                { i3 = mg; }
#pragma unroll
            for (int k = 0; k < 12; ++k)           // static index: stays in regs
                if (k == mk) bv[k] = -INFINITY;
        }

        float es = 0.0f;
#pragma unroll
        for (int e = 0; e < 16; ++e) { pe[e] = __expf(v[e] - x1); es += pe[e]; }
        lds[2048 + wg * 64 + lane] = es;            // after cand (2048 floats)
    }
    __syncthreads();   // sync4

    if (grp == 0) {
        const float s = lds[2048 + lane]       + lds[2048 +  64 + lane]
                      + lds[2048 + 128 + lane] + lds[2048 + 192 + lane];
        const float sinv = 1.0f / s;

        float pr[16];
#pragma unroll
        for (int e = 0; e < 16; ++e) pr[e] = pe[e] * sinv;

        const size_t obase = (size_t)(rg * 64 + lane) * N_EXP + e0;
#pragma unroll
        for (int e4 = 0; e4 < 4; ++e4) {
            float4 pv, mv4;
#pragma unroll
            for (int j = 0; j < 4; ++j) {
                const int g = e0 + e4 * 4 + j;
                ((float*)&pv)[j]  = pr[e4 * 4 + j];
                ((float*)&mv4)[j] = (g == i1 || g == i2 || g == i3) ? 1.0f : 0.0f;
            }
            *(float4*)(out_prob + obase + e4 * 4) = pv;
            *(float4*)(out_mask + obase + e4 * 4) = mv4;
        }

        // once-per-block column sums (importance/load partials)
        float myCol = 0.0f;
#pragma unroll
        for (int e = 0; e < 16; ++e) {
            float se = pr[e];
#pragma unroll
            for (int m = 32; m > 0; m >>= 1) se += __shfl_xor(se, m);
            myCol = (lane == e) ? se : myCol;       // static index per iter
        }
        if (lane < 16)
            pws[(size_t)(e0 + lane) * NBLK + rg] = myCol;
    }
}

// one block per expert: sum its NBLK contiguous partials -> imp[e], load[e]
__global__ __launch_bounds__(256) void reduce_kernel(
    const float* __restrict__ pws,
    float* __restrict__ out_imp, float* __restrict__ out_load) {

    __shared__ float red[4];
    const int e   = blockIdx.x;
    const int tid = threadIdx.x;

    const float* p = pws + (size_t)e * NBLK;
    float s = p[tid] + p[tid + 256];

#pragma unroll
    for (int m = 32; m > 0; m >>= 1) s += __shfl_xor(s, m);
    if ((tid & 63) == 0) red[tid >> 6] = s;
    __syncthreads();
    if (tid == 0) {
        const float t = red[0] + red[1] + red[2] + red[3];
        out_imp[e]  = t;
        out_load[e] = t;
    }
}

extern "C" void kernel_launch(void* const* d_in, const int* in_sizes, int n_in,
                              void* d_out, int out_size, void* d_ws, size_t ws_size,
                              hipStream_t stream) {
    const float* x = (const float*)d_in[0];
    const float* W = (const float*)d_in[1];
    const float* b = (const float*)d_in[2];

    const int N = in_sizes[0] / D_MODEL;   // 32768

    float* o        = (float*)d_out;
    float* out_mask = o;
    float* out_prob = o + (size_t)N * N_EXP;
    float* out_imp  = out_prob + (size_t)N * N_EXP;
    float* out_load = out_imp + N_EXP;

    float* pws = (float*)d_ws;             // 64 * 512 floats = 128 KB

    fused_kernel<<<N / 64, 512, 0, stream>>>(x, W, b, out_mask, out_prob, pws);
    reduce_kernel<<<N_EXP, 256, 0, stream>>>(pws, out_imp, out_load);
}